// Round 8
// baseline (183.635 us; speedup 1.0000x reference)
//
#include <hip/hip_runtime.h>

typedef float  f32x4  __attribute__((ext_vector_type(4)));
typedef short  bf16x8 __attribute__((ext_vector_type(8)));
typedef unsigned short u16;

constexpr int B_ = 4;
constexpr int C_ = 128;
constexpr int N_ = 4096;
constexpr int G_ = 8;
constexpr int CperG = 16;
constexpr float EPS_ = 1e-5f;
constexpr float SCALE_ = 0.08838834764831845f;  // 1/sqrt(C)

__device__ inline u16 f2bf(float f) {
    union { float f; unsigned u; } v; v.f = f;
    unsigned r = v.u + 0x7fffu + ((v.u >> 16) & 1u);  // RNE
    return (u16)(r >> 16);
}
__device__ inline unsigned pk2(float a, float b) {
    return (unsigned)f2bf(a) | ((unsigned)f2bf(b) << 16);
}
// async global->LDS, 16B per lane. LDS dest = wave-uniform base + lane*16.
__device__ inline void gload16(const u16* g, u16* l) {
    __builtin_amdgcn_global_load_lds(
        (const __attribute__((address_space(1))) void*)g,
        (__attribute__((address_space(3))) void*)l, 16, 0, 0);
}

// ---------------- 1. prep: GN partials + weight bf16 conversion ----------------
__global__ __launch_bounds__(256) void prep_kernel(const float* __restrict__ x,
                                                   const float* __restrict__ qw,
                                                   const float* __restrict__ pw,
                                                   float* __restrict__ stats2,
                                                   u16* __restrict__ qwbf,
                                                   u16* __restrict__ pwbf) {
    int blk = blockIdx.x;
    if (blk < 256) {
        __shared__ float rs[4], rss[4];
        int bg = blk >> 3, chunk = blk & 7;
        const float4* xp = (const float4*)(x + (size_t)bg * (CperG * N_)) + chunk * 2048;
        float s = 0.f, ss = 0.f;
        for (int i = threadIdx.x; i < 2048; i += 256) {
            float4 v = xp[i];
            s  += v.x + v.y + v.z + v.w;
            ss += v.x*v.x + v.y*v.y + v.z*v.z + v.w*v.w;
        }
        #pragma unroll
        for (int off = 32; off > 0; off >>= 1) {
            s  += __shfl_down(s, off);
            ss += __shfl_down(ss, off);
        }
        int wv = threadIdx.x >> 6, ln = threadIdx.x & 63;
        if (ln == 0) { rs[wv] = s; rss[wv] = ss; }
        __syncthreads();
        if (threadIdx.x == 0) {
            stats2[blk*2]     = rs[0] + rs[1] + rs[2] + rs[3];
            stats2[blk*2 + 1] = rss[0] + rss[1] + rss[2] + rss[3];
        }
    } else {
        int fidx = ((blk - 256) * 256 + threadIdx.x) * 4;   // 64 blocks * 1024 f32
        float4 v;
        u16* dst;
        if (fidx < 3*C_*C_) { v = *(const float4*)(qw + fidx); dst = qwbf + fidx; }
        else { int j = fidx - 3*C_*C_; v = *(const float4*)(pw + j); dst = pwbf + j; }
        ushort4 o;
        o.x = f2bf(v.x); o.y = f2bf(v.y); o.z = f2bf(v.z); o.w = f2bf(v.w);
        *(ushort4*)dst = o;
    }
}

// ---------------- 2. QKV via MFMA: h AND W staged in LDS ----------------
constexpr int HS = 136;   // padded row stride (u16)

__global__ __launch_bounds__(256, 2) void qkv_kernel(const float* __restrict__ x,
                                                     const float* __restrict__ stats2,
                                                     const float* __restrict__ nw,
                                                     const float* __restrict__ nb,
                                                     const u16* __restrict__ qwbf,
                                                     const float* __restrict__ qb,
                                                     u16* __restrict__ Qt,
                                                     u16* __restrict__ Kt,
                                                     u16* __restrict__ Vb,
                                                     float* __restrict__ qn2,
                                                     int* __restrict__ kmaxI) {
    int n0 = (blockIdx.x & 63) * 64;
    int b  = blockIdx.x >> 6;
    __shared__ u16 hs[64 * HS];
    __shared__ u16 Wl[64 * HS];
    __shared__ float gmean[8], grstd[8];
    int t = threadIdx.x;
    const float invM = 1.f / (float)(CperG * N_);
    if (t < 8) {
        const float* sp = stats2 + (size_t)(b*G_ + t)*16;
        float S = 0.f, SS = 0.f;
        #pragma unroll
        for (int k2 = 0; k2 < 8; ++k2) { S += sp[k2*2]; SS += sp[k2*2 + 1]; }
        float mean = S * invM;
        gmean[t] = mean;
        grstd[t] = rsqrtf(SS * invM - mean*mean + EPS_);
    }
    __syncthreads();
    #pragma unroll
    for (int r = 0; r < 8; ++r) {
        int idx = t + (r << 8);
        int c = idx >> 4, n4 = idx & 15;
        int g = c >> 4;
        float wgt = nw[c] * grstd[g];
        float bia = nb[c] - gmean[g] * wgt;
        float4 xv = *(const float4*)(x + ((size_t)(b*C_ + c))*N_ + n0 + n4*4);
        int base = (n4*4) * HS + c;
        hs[base         ] = f2bf(xv.x*wgt + bia);
        hs[base +     HS] = f2bf(xv.y*wgt + bia);
        hs[base + 2 * HS] = f2bf(xv.z*wgt + bia);
        hs[base + 3 * HS] = f2bf(xv.w*wgt + bia);
    }
    __syncthreads();
    int w = t >> 6, lane = t & 63, lo = lane & 15, hi = lane >> 4;
    bf16x8 hf[4];
    #pragma unroll
    for (int ch = 0; ch < 4; ++ch)
        hf[ch] = *(const bf16x8*)(hs + (16*w + lo)*HS + 32*ch + 8*hi);

    float nq = 0.f, nk = 0.f;
    for (int ck = 0; ck < 6; ++ck) {
        {
            int r = t >> 2, p = t & 3;
            const u16* src = qwbf + (size_t)(ck*64 + r)*C_ + p*32;
            u16* dst = Wl + r*HS + p*32;
            #pragma unroll
            for (int k2 = 0; k2 < 4; ++k2)
                *(uint4*)(dst + 8*k2) = *(const uint4*)(src + 8*k2);
        }
        __syncthreads();
        #pragma unroll
        for (int ot = 0; ot < 4; ++ot) {
            int o16 = ck*64 + ot*16;
            bf16x8 wf[4];
            #pragma unroll
            for (int ch = 0; ch < 4; ++ch)
                wf[ch] = *(const bf16x8*)(Wl + (ot*16 + lo)*HS + 32*ch + 8*hi);
            if (o16 < 2*C_) {
                f32x4 acc = (f32x4){0.f, 0.f, 0.f, 0.f};
                #pragma unroll
                for (int ch = 0; ch < 4; ++ch)
                    acc = __builtin_amdgcn_mfma_f32_16x16x32_bf16(wf[ch], hf[ch], acc, 0, 0, 0);
                float4 bv = *(const float4*)(qb + o16 + 4*hi);
                int n = n0 + 16*w + lo;
                ushort4 o4;
                if (o16 < C_) {
                    float q0 = (acc[0] + bv.x) * SCALE_;
                    float q1 = (acc[1] + bv.y) * SCALE_;
                    float q2 = (acc[2] + bv.z) * SCALE_;
                    float q3 = (acc[3] + bv.w) * SCALE_;
                    nq += (q0*q0 + q1*q1) + (q2*q2 + q3*q3);
                    o4.x = f2bf(q0); o4.y = f2bf(q1); o4.z = f2bf(q2); o4.w = f2bf(q3);
                    *(ushort4*)(Qt + ((size_t)b*N_ + n)*C_ + o16 + 4*hi) = o4;
                } else {
                    float k0 = acc[0] + bv.x, k1 = acc[1] + bv.y;
                    float k2 = acc[2] + bv.z, k3 = acc[3] + bv.w;
                    nk += (k0*k0 + k1*k1) + (k2*k2 + k3*k3);
                    o4.x = f2bf(k0); o4.y = f2bf(k1); o4.z = f2bf(k2); o4.w = f2bf(k3);
                    *(ushort4*)(Kt + ((size_t)b*N_ + n)*C_ + (o16 - C_) + 4*hi) = o4;
                }
            } else {
                f32x4 acc = (f32x4){0.f, 0.f, 0.f, 0.f};
                #pragma unroll
                for (int ch = 0; ch < 4; ++ch)
                    acc = __builtin_amdgcn_mfma_f32_16x16x32_bf16(hf[ch], wf[ch], acc, 0, 0, 0);
                float bia = qb[o16 + lo];
                ushort4 o4;
                o4.x = f2bf(acc[0] + bia);
                o4.y = f2bf(acc[1] + bia);
                o4.z = f2bf(acc[2] + bia);
                o4.w = f2bf(acc[3] + bia);
                *(ushort4*)(Vb + ((size_t)b*C_ + (o16 - 2*C_) + lo)*N_ + n0 + 16*w + 4*hi) = o4;
            }
        }
        __syncthreads();
    }
    nq += __shfl_xor(nq, 16); nq += __shfl_xor(nq, 32);
    nk += __shfl_xor(nk, 16); nk += __shfl_xor(nk, 32);
    if (lane < 16) qn2[(size_t)b*N_ + n0 + 16*w + lo] = nq;
    #pragma unroll
    for (int off = 1; off < 16; off <<= 1)
        nk = fmaxf(nk, __shfl_xor(nk, off));
    if (lane == 0) atomicMax(&kmaxI[b], __float_as_int(nk));
}

// ------------- 3. Tq=64, double-buffered LDS, bound-softmax MFMA attention -------------
// 256 blocks (1/CU), 512 threads, 8 waves = (qt: 4 x 16-q tiles) x (ks: 2 x 32-key
// halves of a 64-key tile). Double-buffered K/V staging via global_load_lds: loads
// for tile t+1 issued before compute on tile t; ONE barrier/iter covers the drain.
constexpr int PS = 40;    // P row stride in u16

__global__ __launch_bounds__(512, 2) void attn_kernel(const u16* __restrict__ Qt,
                                                      const u16* __restrict__ Kt,
                                                      const u16* __restrict__ Vb,
                                                      const float* __restrict__ qn2,
                                                      const int* __restrict__ kmaxI,
                                                      const u16* __restrict__ pwbf,
                                                      const float* __restrict__ pb,
                                                      const float* __restrict__ x,
                                                      float* __restrict__ out) {
    int lb = blockIdx.x;
    int b  = lb & 3;                       // XCD-swizzle: one batch per XCD
    int i0 = 64 * (lb >> 2);
    int t = threadIdx.x;
    int w = t >> 6, lane = t & 63, lo = lane & 15, hi = lane >> 4;
    int qt = w >> 1, ks = w & 1;

    const u16* Qb = Qt + (size_t)b*N_*C_;
    const u16* Kb = Kt + (size_t)b*N_*C_;
    const u16* Vv = Vb + (size_t)b*C_*N_;

    __shared__ __align__(16) u16 KV[2][16384];   // per buf: Kl[64k][128c] | Vl[128c][64k]
    __shared__ __align__(16) u16 Ps[8][16 * PS];
    __shared__ float lW[8][16];
    float* Ob = (float*)KV;                      // epilogue overlay: 64*132 f32 = 33.8 KB

    float kmax = sqrtf(__int_as_float(kmaxI[b]));
    float mq = sqrtf(qn2[(size_t)b*N_ + i0 + 16*qt + lo]) * kmax * 1.02f + 1e-6f;

    bf16x8 qf[4];
    #pragma unroll
    for (int ch = 0; ch < 4; ++ch)
        qf[ch] = *(const bf16x8*)(Qb + (size_t)(i0 + 16*qt + lo)*C_ + 32*ch + 8*hi);

    f32x4 acc[8];
    #pragma unroll
    for (int ct = 0; ct < 8; ++ct) acc[ct] = (f32x4){0.f, 0.f, 0.f, 0.f};
    float psum = 0.f;

    int srow = lane >> 4, schnk = lane & 15;     // K staging (4 rows / gload16)
    int vrow = lane >> 3, vchnk = lane & 7;      // V staging (8 rows / gload16)

    // prime buffer 0
    {
        u16* Kl = KV[0];
        u16* Vl = KV[0] + 8192;
        if (w < 4) {
            #pragma unroll
            for (int j = 0; j < 4; ++j) {
                int k0 = 16*w + 4*j;
                int r  = k0 + srow;
                gload16(Kb + (size_t)r*C_ + (schnk ^ (r & 15))*8, Kl + k0*128);
            }
        } else {
            #pragma unroll
            for (int j = 0; j < 4; ++j) {
                int c0 = 32*(w - 4) + 8*j;
                int ch = c0 + vrow;
                gload16(Vv + (size_t)ch*N_ + (vchnk ^ (ch & 7))*8, Vl + c0*64);
            }
        }
    }
    __syncthreads();

    for (int it = 0; it < 64; ++it) {
        int cur = it & 1;
        // ---- prefetch tile it+1 into the other buffer (async) ----
        if (it < 63) {
            int tile0 = (it + 1) * 64;
            u16* Kl = KV[cur ^ 1];
            u16* Vl = KV[cur ^ 1] + 8192;
            if (w < 4) {
                #pragma unroll
                for (int j = 0; j < 4; ++j) {
                    int k0 = 16*w + 4*j;
                    int r  = k0 + srow;
                    gload16(Kb + (size_t)(tile0 + r)*C_ + (schnk ^ (r & 15))*8, Kl + k0*128);
                }
            } else {
                #pragma unroll
                for (int j = 0; j < 4; ++j) {
                    int c0 = 32*(w - 4) + 8*j;
                    int ch = c0 + vrow;
                    gload16(Vv + (size_t)ch*N_ + tile0 + (vchnk ^ (ch & 7))*8, Vl + c0*64);
                }
            }
        }
        // ---- compute on current buffer ----
        u16* Kl = KV[cur];
        u16* Vl = KV[cur] + 8192;
        f32x4 s0 = (f32x4){0.f,0.f,0.f,0.f}, s1 = s0;
        int kk0 = 32*ks + lo;
        #pragma unroll
        for (int ch = 0; ch < 4; ++ch) {
            bf16x8 k0f = *(const bf16x8*)(Kl + kk0*128        + ((4*ch + hi) ^ lo)*8);
            bf16x8 k1f = *(const bf16x8*)(Kl + (kk0 + 16)*128 + ((4*ch + hi) ^ lo)*8);
            s0 = __builtin_amdgcn_mfma_f32_16x16x32_bf16(k0f, qf[ch], s0, 0, 0, 0);
            s1 = __builtin_amdgcn_mfma_f32_16x16x32_bf16(k1f, qf[ch], s1, 0, 0, 0);
        }
        // ---- bound softmax: p = exp(S - m_q), no reductions ----
        {
            float p0 = __expf(s0[0]-mq), p1 = __expf(s0[1]-mq);
            float p2 = __expf(s0[2]-mq), p3 = __expf(s0[3]-mq);
            psum += (p0+p1)+(p2+p3);
            uint2 pk; pk.x = pk2(p0,p1); pk.y = pk2(p2,p3);
            *(uint2*)(&Ps[w][lo*PS + 4*hi]) = pk;
        }
        {
            float p0 = __expf(s1[0]-mq), p1 = __expf(s1[1]-mq);
            float p2 = __expf(s1[2]-mq), p3 = __expf(s1[3]-mq);
            psum += (p0+p1)+(p2+p3);
            uint2 pk; pk.x = pk2(p0,p1); pk.y = pk2(p2,p3);
            *(uint2*)(&Ps[w][lo*PS + 16 + 4*hi]) = pk;
        }
        // ---- PV: A = P (wave-private), B = V frags from LDS ----
        bf16x8 pa = *(const bf16x8*)(&Ps[w][lo*PS + 8*hi]);
        #pragma unroll
        for (int ct = 0; ct < 8; ++ct) {
            int cc = 16*ct + lo;
            bf16x8 vf = *(const bf16x8*)(Vl + cc*64 + ((4*ks + hi) ^ (cc & 7))*8);
            acc[ct] = __builtin_amdgcn_mfma_f32_16x16x32_bf16(pa, vf, acc[ct], 0, 0, 0);
        }
        __syncthreads();   // drains prefetch (covered by compute) + guards buffer reuse
    }

    // ---------------- combine ks-halves (plain adds: shared m_q) ----------------
    psum += __shfl_xor(psum, 16);
    psum += __shfl_xor(psum, 32);
    if (lane < 16) lW[w][lo] = psum;
    __syncthreads();
    for (int i = 0; i < 2; ++i) {
        if (ks == i) {
            #pragma unroll
            for (int ct = 0; ct < 8; ++ct)
                #pragma unroll
                for (int r = 0; r < 4; ++r) {
                    int q = 16*qt + 4*hi + r, c = 16*ct + lo;
                    if (i == 0) Ob[q*132 + c]  = acc[ct][r];
                    else        Ob[q*132 + c] += acc[ct][r];
                }
        }
        __syncthreads();
    }
    // ---------------- proj + bias + residual ----------------
    float linv = 1.f / (lW[2*qt][lo] + lW[2*qt + 1][lo]);   // query 16qt+lo
    bf16x8 aa[4];
    #pragma unroll
    for (int ch = 0; ch < 4; ++ch) {
        float4 ua = *(const float4*)(Ob + (16*qt + lo)*132 + 32*ch + 8*hi);
        float4 ub = *(const float4*)(Ob + (16*qt + lo)*132 + 32*ch + 8*hi + 4);
        union { bf16x8 h; unsigned u[4]; } pkd;
        pkd.u[0] = pk2(ua.x*linv, ua.y*linv);
        pkd.u[1] = pk2(ua.z*linv, ua.w*linv);
        pkd.u[2] = pk2(ub.x*linv, ub.y*linv);
        pkd.u[3] = pk2(ub.z*linv, ub.w*linv);
        aa[ch] = pkd.h;
    }
    #pragma unroll
    for (int ot = 0; ot < 4; ++ot) {
        int ob = 64*ks + 16*ot;
        f32x4 pr = (f32x4){0.f, 0.f, 0.f, 0.f};
        #pragma unroll
        for (int ch = 0; ch < 4; ++ch) {
            bf16x8 bw = *(const bf16x8*)(pwbf + (size_t)(ob + lo)*C_ + 32*ch + 8*hi);
            pr = __builtin_amdgcn_mfma_f32_16x16x32_bf16(aa[ch], bw, pr, 0, 0, 0);
        }
        int o = ob + lo;
        float pbv = pb[o];
        size_t base = ((size_t)(b*C_ + o))*N_ + i0 + 16*qt + 4*hi;
        float4 xr = *(const float4*)(x + base);
        float4 res;
        res.x = xr.x + pr[0] + pbv;
        res.y = xr.y + pr[1] + pbv;
        res.z = xr.z + pr[2] + pbv;
        res.w = xr.w + pr[3] + pbv;
        *(float4*)(out + base) = res;
    }
}

extern "C" void kernel_launch(void* const* d_in, const int* in_sizes, int n_in,
                              void* d_out, int out_size, void* d_ws, size_t ws_size,
                              hipStream_t stream) {
    const float* x  = (const float*)d_in[0];
    const float* nw = (const float*)d_in[1];
    const float* nb = (const float*)d_in[2];
    const float* qw = (const float*)d_in[3];
    const float* qb = (const float*)d_in[4];
    const float* pw = (const float*)d_in[5];
    const float* pb = (const float*)d_in[6];
    float* out = (float*)d_out;

    // ws: [stats2 2KB][qn2 64KB][kmaxI 256B][qwbf 96KB][pwbf 32KB][Qt 4MB][Kt 4MB][Vb 4MB]
    char* p = (char*)d_ws;
    float* stats2 = (float*)p;                 p += 2048;
    float* qn2    = (float*)p;                 p += (size_t)B_*N_*4;
    int*   kmaxI  = (int*)p;                   p += 256;
    u16*   qwbf   = (u16*)p;                   p += (size_t)3*C_*C_*2;
    u16*   pwbf   = (u16*)p;                   p += (size_t)C_*C_*2;
    u16*   Qt     = (u16*)p;                   p += (size_t)B_*N_*C_*2;
    u16*   Kt     = (u16*)p;                   p += (size_t)B_*N_*C_*2;
    u16*   Vb     = (u16*)p;

    prep_kernel<<<dim3(320), 256, 0, stream>>>(x, qw, pw, stats2, qwbf, pwbf);
    qkv_kernel<<<dim3(256), 256, 0, stream>>>(x, stats2, nw, nb, qwbf, qb,
                                              Qt, Kt, Vb, qn2, kmaxI);
    attn_kernel<<<dim3(256), 512, 0, stream>>>(Qt, Kt, Vb, qn2, kmaxI,
                                               pwbf, pb, x, out);
}

// Round 9
// 169.503 us; speedup vs baseline: 1.0834x; 1.0834x over previous
//
#include <hip/hip_runtime.h>

typedef float  f32x4   __attribute__((ext_vector_type(4)));
typedef float  f32x16  __attribute__((ext_vector_type(16)));
typedef short  bf16x8  __attribute__((ext_vector_type(8)));
typedef unsigned short u16;

constexpr int B_ = 4;
constexpr int C_ = 128;
constexpr int N_ = 4096;
constexpr int G_ = 8;
constexpr int CperG = 16;
constexpr float EPS_ = 1e-5f;
constexpr float SCALE_ = 0.08838834764831845f;  // 1/sqrt(C)

__device__ inline u16 f2bf(float f) {
    union { float f; unsigned u; } v; v.f = f;
    unsigned r = v.u + 0x7fffu + ((v.u >> 16) & 1u);  // RNE
    return (u16)(r >> 16);
}
__device__ inline unsigned pk2(float a, float b) {
    return (unsigned)f2bf(a) | ((unsigned)f2bf(b) << 16);
}
// async global->LDS, 16B per lane. LDS dest = wave-uniform base + lane*16.
__device__ inline void gload16(const u16* g, u16* l) {
    __builtin_amdgcn_global_load_lds(
        (const __attribute__((address_space(1))) void*)g,
        (__attribute__((address_space(3))) void*)l, 16, 0, 0);
}

// ---------------- 1. prep: GN partials + weight bf16 conversion ----------------
__global__ __launch_bounds__(256) void prep_kernel(const float* __restrict__ x,
                                                   const float* __restrict__ qw,
                                                   const float* __restrict__ pw,
                                                   float* __restrict__ stats2,
                                                   u16* __restrict__ qwbf,
                                                   u16* __restrict__ pwbf) {
    int blk = blockIdx.x;
    if (blk < 256) {
        __shared__ float rs[4], rss[4];
        int bg = blk >> 3, chunk = blk & 7;
        const float4* xp = (const float4*)(x + (size_t)bg * (CperG * N_)) + chunk * 2048;
        float s = 0.f, ss = 0.f;
        for (int i = threadIdx.x; i < 2048; i += 256) {
            float4 v = xp[i];
            s  += v.x + v.y + v.z + v.w;
            ss += v.x*v.x + v.y*v.y + v.z*v.z + v.w*v.w;
        }
        #pragma unroll
        for (int off = 32; off > 0; off >>= 1) {
            s  += __shfl_down(s, off);
            ss += __shfl_down(ss, off);
        }
        int wv = threadIdx.x >> 6, ln = threadIdx.x & 63;
        if (ln == 0) { rs[wv] = s; rss[wv] = ss; }
        __syncthreads();
        if (threadIdx.x == 0) {
            stats2[blk*2]     = rs[0] + rs[1] + rs[2] + rs[3];
            stats2[blk*2 + 1] = rss[0] + rss[1] + rss[2] + rss[3];
        }
    } else {
        int fidx = ((blk - 256) * 256 + threadIdx.x) * 4;   // 64 blocks * 1024 f32
        float4 v;
        u16* dst;
        if (fidx < 3*C_*C_) { v = *(const float4*)(qw + fidx); dst = qwbf + fidx; }
        else { int j = fidx - 3*C_*C_; v = *(const float4*)(pw + j); dst = pwbf + j; }
        ushort4 o;
        o.x = f2bf(v.x); o.y = f2bf(v.y); o.z = f2bf(v.z); o.w = f2bf(v.w);
        *(ushort4*)dst = o;
    }
}

// ---------------- 2. QKV via MFMA: h AND W staged in LDS ----------------
constexpr int HS = 136;   // padded row stride (u16)

__global__ __launch_bounds__(256, 2) void qkv_kernel(const float* __restrict__ x,
                                                     const float* __restrict__ stats2,
                                                     const float* __restrict__ nw,
                                                     const float* __restrict__ nb,
                                                     const u16* __restrict__ qwbf,
                                                     const float* __restrict__ qb,
                                                     u16* __restrict__ Qt,
                                                     u16* __restrict__ Kt,
                                                     u16* __restrict__ Vb,
                                                     float* __restrict__ qn2,
                                                     int* __restrict__ kmaxI) {
    int n0 = (blockIdx.x & 63) * 64;
    int b  = blockIdx.x >> 6;
    __shared__ u16 hs[64 * HS];
    __shared__ u16 Wl[64 * HS];
    __shared__ float gmean[8], grstd[8];
    int t = threadIdx.x;
    const float invM = 1.f / (float)(CperG * N_);
    if (t < 8) {
        const float* sp = stats2 + (size_t)(b*G_ + t)*16;
        float S = 0.f, SS = 0.f;
        #pragma unroll
        for (int k2 = 0; k2 < 8; ++k2) { S += sp[k2*2]; SS += sp[k2*2 + 1]; }
        float mean = S * invM;
        gmean[t] = mean;
        grstd[t] = rsqrtf(SS * invM - mean*mean + EPS_);
    }
    __syncthreads();
    #pragma unroll
    for (int r = 0; r < 8; ++r) {
        int idx = t + (r << 8);
        int c = idx >> 4, n4 = idx & 15;
        int g = c >> 4;
        float wgt = nw[c] * grstd[g];
        float bia = nb[c] - gmean[g] * wgt;
        float4 xv = *(const float4*)(x + ((size_t)(b*C_ + c))*N_ + n0 + n4*4);
        int base = (n4*4) * HS + c;
        hs[base         ] = f2bf(xv.x*wgt + bia);
        hs[base +     HS] = f2bf(xv.y*wgt + bia);
        hs[base + 2 * HS] = f2bf(xv.z*wgt + bia);
        hs[base + 3 * HS] = f2bf(xv.w*wgt + bia);
    }
    __syncthreads();
    int w = t >> 6, lane = t & 63, lo = lane & 15, hi = lane >> 4;
    bf16x8 hf[4];
    #pragma unroll
    for (int ch = 0; ch < 4; ++ch)
        hf[ch] = *(const bf16x8*)(hs + (16*w + lo)*HS + 32*ch + 8*hi);

    float nq = 0.f, nk = 0.f;
    for (int ck = 0; ck < 6; ++ck) {
        {
            int r = t >> 2, p = t & 3;
            const u16* src = qwbf + (size_t)(ck*64 + r)*C_ + p*32;
            u16* dst = Wl + r*HS + p*32;
            #pragma unroll
            for (int k2 = 0; k2 < 4; ++k2)
                *(uint4*)(dst + 8*k2) = *(const uint4*)(src + 8*k2);
        }
        __syncthreads();
        #pragma unroll
        for (int ot = 0; ot < 4; ++ot) {
            int o16 = ck*64 + ot*16;
            bf16x8 wf[4];
            #pragma unroll
            for (int ch = 0; ch < 4; ++ch)
                wf[ch] = *(const bf16x8*)(Wl + (ot*16 + lo)*HS + 32*ch + 8*hi);
            if (o16 < 2*C_) {
                f32x4 acc = (f32x4){0.f, 0.f, 0.f, 0.f};
                #pragma unroll
                for (int ch = 0; ch < 4; ++ch)
                    acc = __builtin_amdgcn_mfma_f32_16x16x32_bf16(wf[ch], hf[ch], acc, 0, 0, 0);
                float4 bv = *(const float4*)(qb + o16 + 4*hi);
                int n = n0 + 16*w + lo;
                ushort4 o4;
                if (o16 < C_) {
                    float q0 = (acc[0] + bv.x) * SCALE_;
                    float q1 = (acc[1] + bv.y) * SCALE_;
                    float q2 = (acc[2] + bv.z) * SCALE_;
                    float q3 = (acc[3] + bv.w) * SCALE_;
                    nq += (q0*q0 + q1*q1) + (q2*q2 + q3*q3);
                    o4.x = f2bf(q0); o4.y = f2bf(q1); o4.z = f2bf(q2); o4.w = f2bf(q3);
                    *(ushort4*)(Qt + ((size_t)b*N_ + n)*C_ + o16 + 4*hi) = o4;
                } else {
                    float k0 = acc[0] + bv.x, k1 = acc[1] + bv.y;
                    float k2 = acc[2] + bv.z, k3 = acc[3] + bv.w;
                    nk += (k0*k0 + k1*k1) + (k2*k2 + k3*k3);
                    o4.x = f2bf(k0); o4.y = f2bf(k1); o4.z = f2bf(k2); o4.w = f2bf(k3);
                    *(ushort4*)(Kt + ((size_t)b*N_ + n)*C_ + (o16 - C_) + 4*hi) = o4;
                }
            } else {
                f32x4 acc = (f32x4){0.f, 0.f, 0.f, 0.f};
                #pragma unroll
                for (int ch = 0; ch < 4; ++ch)
                    acc = __builtin_amdgcn_mfma_f32_16x16x32_bf16(hf[ch], wf[ch], acc, 0, 0, 0);
                float bia = qb[o16 + lo];
                ushort4 o4;
                o4.x = f2bf(acc[0] + bia);
                o4.y = f2bf(acc[1] + bia);
                o4.z = f2bf(acc[2] + bia);
                o4.w = f2bf(acc[3] + bia);
                *(ushort4*)(Vb + ((size_t)b*C_ + (o16 - 2*C_) + lo)*N_ + n0 + 16*w + 4*hi) = o4;
            }
        }
        __syncthreads();
    }
    nq += __shfl_xor(nq, 16); nq += __shfl_xor(nq, 32);
    nk += __shfl_xor(nk, 16); nk += __shfl_xor(nk, 32);
    if (lane < 16) qn2[(size_t)b*N_ + n0 + 16*w + lo] = nq;
    #pragma unroll
    for (int off = 1; off < 16; off <<= 1)
        nk = fmaxf(nk, __shfl_xor(nk, off));
    if (lane == 0) atomicMax(&kmaxI[b], __float_as_int(nk));
}

// ------------- 3. 32x32-MFMA attention: register-direct P, halved LDS reads -------------
// 256 blocks, 512 thr, 8 waves = (qt: 2 x 32-q) x (ks: 4 x 32-key strips of a
// 128-key tile). Double-buffered K/V staging (128 KB). P never touches LDS: the
// S C-layout rows per half-wave are exactly the k-slots two K=16 PV mfmas need
// (permutation-proof: identical k-reindex on A and B operands).
__global__ __launch_bounds__(512, 2) void attn_kernel(const u16* __restrict__ Qt,
                                                      const u16* __restrict__ Kt,
                                                      const u16* __restrict__ Vb,
                                                      const float* __restrict__ qn2,
                                                      const int* __restrict__ kmaxI,
                                                      const u16* __restrict__ pwbf,
                                                      const float* __restrict__ pb,
                                                      const float* __restrict__ x,
                                                      float* __restrict__ out) {
    int lb = blockIdx.x;
    int b  = lb & 3;                       // XCD-swizzle: one batch per XCD-pair
    int i0 = 64 * (lb >> 2);
    int t = threadIdx.x;
    int w = t >> 6, lane = t & 63;
    int l31 = lane & 31, l15 = lane & 15, h = lane >> 5;
    int qt = w >> 2, ks = w & 3;

    const u16* Qb = Qt + (size_t)b*N_*C_;
    const u16* Kb = Kt + (size_t)b*N_*C_;
    const u16* Vv = Vb + (size_t)b*C_*N_;

    __shared__ __align__(16) u16 KV[2][32768];   // per buf: K[128k][128c] | V[128c][128k]
    __shared__ float lW[8][32];
    float* Ob = (float*)KV;                      // epilogue overlay (64*132 f32, in KV[0])

    float kmax = sqrtf(__int_as_float(kmaxI[b]));
    float mq = sqrtf(qn2[(size_t)b*N_ + i0 + 32*qt + l31]) * kmax * 1.02f + 1e-6f;

    // persistent Q B-frags (query = i0 + 32qt + l31)
    bf16x8 qf[8];
    #pragma unroll
    for (int ch = 0; ch < 8; ++ch)
        qf[ch] = *(const bf16x8*)(Qb + (size_t)(i0 + 32*qt + l31)*C_ + 16*ch + 8*h);

    f32x16 acc[4];
    #pragma unroll
    for (int ct = 0; ct < 4; ++ct)
        #pragma unroll
        for (int r = 0; r < 16; ++r) acc[ct][r] = 0.f;
    float psum = 0.f;

    int srow = lane >> 4, schnk = lane & 15;

    auto stage = [&](int tile0, u16* buf) {
        if (w < 4) {
            #pragma unroll
            for (int j = 0; j < 8; ++j) {
                int k0 = 32*w + 4*j;
                int r  = k0 + srow;
                gload16(Kb + (size_t)(tile0 + r)*C_ + (schnk ^ (r & 15))*8, buf + k0*128);
            }
        } else {
            #pragma unroll
            for (int j = 0; j < 8; ++j) {
                int c0 = 32*(w - 4) + 4*j;
                int ch = c0 + srow;
                gload16(Vv + (size_t)ch*N_ + tile0 + (schnk ^ (ch & 15))*8,
                        buf + 16384 + c0*128);
            }
        }
    };

    stage(0, KV[0]);
    __syncthreads();

    for (int it = 0; it < 32; ++it) {
        int cur = it & 1;
        if (it < 31) stage((it + 1) * 128, KV[cur ^ 1]);
        u16* Kl = KV[cur];
        u16* Vl = KV[cur] + 16384;
        // ---- QK: one 32x32 S^T tile (keys 32ks+l31-rows, queries 32qt+cols) ----
        f32x16 s;
        #pragma unroll
        for (int r = 0; r < 16; ++r) s[r] = 0.f;
        int krow = (32*ks + l31) * 128;
        #pragma unroll
        for (int ch = 0; ch < 8; ++ch) {
            bf16x8 kf = *(const bf16x8*)(Kl + krow + ((2*ch + h) ^ l15)*8);
            s = __builtin_amdgcn_mfma_f32_32x32x16_bf16(kf, qf[ch], s, 0, 0, 0);
        }
        // ---- bound softmax: p = exp(S - m_q), no reductions, no LDS ----
        float p[16];
        #pragma unroll
        for (int r = 0; r < 16; ++r) {
            p[r] = __expf(s[r] - mq);
            psum += p[r];
        }
        union { bf16x8 v; unsigned u[4]; } pf1, pf2;
        pf1.u[0] = pk2(p[0],  p[1]);  pf1.u[1] = pk2(p[2],  p[3]);
        pf1.u[2] = pk2(p[4],  p[5]);  pf1.u[3] = pk2(p[6],  p[7]);
        pf2.u[0] = pk2(p[8],  p[9]);  pf2.u[1] = pk2(p[10], p[11]);
        pf2.u[2] = pk2(p[12], p[13]); pf2.u[3] = pk2(p[14], p[15]);
        // ---- PV: A = V^T (LDS, key-arranged to match P's register rows) ----
        #pragma unroll
        for (int ct = 0; ct < 4; ++ct) {
            int vbase = (32*ct + l31) * 128;
            union { bf16x8 v; long long q[2]; } v1, v2;
            v1.q[0] = *(const long long*)(Vl + vbase + (2*((4*ks    ) ^ l15) + h)*4);
            v1.q[1] = *(const long long*)(Vl + vbase + (2*((4*ks + 1) ^ l15) + h)*4);
            v2.q[0] = *(const long long*)(Vl + vbase + (2*((4*ks + 2) ^ l15) + h)*4);
            v2.q[1] = *(const long long*)(Vl + vbase + (2*((4*ks + 3) ^ l15) + h)*4);
            acc[ct] = __builtin_amdgcn_mfma_f32_32x32x16_bf16(v1.v, pf1.v, acc[ct], 0, 0, 0);
            acc[ct] = __builtin_amdgcn_mfma_f32_32x32x16_bf16(v2.v, pf2.v, acc[ct], 0, 0, 0);
        }
        __syncthreads();   // prefetch drained (covered by compute) + buffer reuse guard
    }

    // ---------------- combine ks strips (plain adds: shared m_q) ----------------
    psum += __shfl_xor(psum, 32);
    if (lane < 32) lW[w][l31] = psum;
    for (int i = 0; i < 4; ++i) {
        if (ks == i) {
            int q = 32*qt + l31;
            #pragma unroll
            for (int ct = 0; ct < 4; ++ct)
                #pragma unroll
                for (int qd = 0; qd < 4; ++qd) {
                    int c = 32*ct + 8*qd + 4*h;
                    float4 vv;
                    vv.x = acc[ct][4*qd + 0];
                    vv.y = acc[ct][4*qd + 1];
                    vv.z = acc[ct][4*qd + 2];
                    vv.w = acc[ct][4*qd + 3];
                    if (i == 0) {
                        *(float4*)(Ob + q*132 + c) = vv;
                    } else {
                        float4 o = *(const float4*)(Ob + q*132 + c);
                        o.x += vv.x; o.y += vv.y; o.z += vv.z; o.w += vv.w;
                        *(float4*)(Ob + q*132 + c) = o;
                    }
                }
        }
        __syncthreads();
    }
    // ---------------- proj + bias + residual (16x16x32, as before) ----------------
    int lo = lane & 15, hi = lane >> 4;
    int qtile = w >> 1, os = w & 1;
    int q = 16*qtile + lo;
    int qg = 4*(q >> 5), qc = q & 31;
    float linv = 1.f / (lW[qg][qc] + lW[qg+1][qc] + lW[qg+2][qc] + lW[qg+3][qc]);
    bf16x8 aa[4];
    #pragma unroll
    for (int ch = 0; ch < 4; ++ch) {
        float4 ua = *(const float4*)(Ob + q*132 + 32*ch + 8*hi);
        float4 ub = *(const float4*)(Ob + q*132 + 32*ch + 8*hi + 4);
        union { bf16x8 hh; unsigned u[4]; } pkd;
        pkd.u[0] = pk2(ua.x*linv, ua.y*linv);
        pkd.u[1] = pk2(ua.z*linv, ua.w*linv);
        pkd.u[2] = pk2(ub.x*linv, ub.y*linv);
        pkd.u[3] = pk2(ub.z*linv, ub.w*linv);
        aa[ch] = pkd.hh;
    }
    #pragma unroll
    for (int ot = 0; ot < 4; ++ot) {
        int ob = 64*os + 16*ot;
        f32x4 pr = (f32x4){0.f, 0.f, 0.f, 0.f};
        #pragma unroll
        for (int ch = 0; ch < 4; ++ch) {
            bf16x8 bw = *(const bf16x8*)(pwbf + (size_t)(ob + lo)*C_ + 32*ch + 8*hi);
            pr = __builtin_amdgcn_mfma_f32_16x16x32_bf16(aa[ch], bw, pr, 0, 0, 0);
        }
        int o = ob + lo;
        float pbv = pb[o];
        size_t base = ((size_t)(b*C_ + o))*N_ + i0 + 16*qtile + 4*hi;
        float4 xr = *(const float4*)(x + base);
        float4 res;
        res.x = xr.x + pr[0] + pbv;
        res.y = xr.y + pr[1] + pbv;
        res.z = xr.z + pr[2] + pbv;
        res.w = xr.w + pr[3] + pbv;
        *(float4*)(out + base) = res;
    }
}

extern "C" void kernel_launch(void* const* d_in, const int* in_sizes, int n_in,
                              void* d_out, int out_size, void* d_ws, size_t ws_size,
                              hipStream_t stream) {
    const float* x  = (const float*)d_in[0];
    const float* nw = (const float*)d_in[1];
    const float* nb = (const float*)d_in[2];
    const float* qw = (const float*)d_in[3];
    const float* qb = (const float*)d_in[4];
    const float* pw = (const float*)d_in[5];
    const float* pb = (const float*)d_in[6];
    float* out = (float*)d_out;

    // ws: [stats2 2KB][qn2 64KB][kmaxI 256B][qwbf 96KB][pwbf 32KB][Qt 4MB][Kt 4MB][Vb 4MB]
    char* p = (char*)d_ws;
    float* stats2 = (float*)p;                 p += 2048;
    float* qn2    = (float*)p;                 p += (size_t)B_*N_*4;
    int*   kmaxI  = (int*)p;                   p += 256;
    u16*   qwbf   = (u16*)p;                   p += (size_t)3*C_*C_*2;
    u16*   pwbf   = (u16*)p;                   p += (size_t)C_*C_*2;
    u16*   Qt     = (u16*)p;                   p += (size_t)B_*N_*C_*2;
    u16*   Kt     = (u16*)p;                   p += (size_t)B_*N_*C_*2;
    u16*   Vb     = (u16*)p;

    prep_kernel<<<dim3(320), 256, 0, stream>>>(x, qw, pw, stats2, qwbf, pwbf);
    qkv_kernel<<<dim3(256), 256, 0, stream>>>(x, stats2, nw, nb, qwbf, qb,
                                              Qt, Kt, Vb, qn2, kmaxI);
    attn_kernel<<<dim3(256), 512, 0, stream>>>(Qt, Kt, Vb, qn2, kmaxI,
                                               pwbf, pb, x, out);
}

// Round 10
// 152.834 us; speedup vs baseline: 1.2015x; 1.1091x over previous
//
#include <hip/hip_runtime.h>

typedef float  f32x4   __attribute__((ext_vector_type(4)));
typedef float  f32x16  __attribute__((ext_vector_type(16)));
typedef short  bf16x8  __attribute__((ext_vector_type(8)));
typedef unsigned short u16;

constexpr int B_ = 4;
constexpr int C_ = 128;
constexpr int N_ = 4096;
constexpr int G_ = 8;
constexpr int CperG = 16;
constexpr float EPS_ = 1e-5f;
constexpr float SCALE_ = 0.08838834764831845f;  // 1/sqrt(C)

__device__ inline u16 f2bf(float f) {
    union { float f; unsigned u; } v; v.f = f;
    unsigned r = v.u + 0x7fffu + ((v.u >> 16) & 1u);  // RNE
    return (u16)(r >> 16);
}
__device__ inline unsigned pk2(float a, float b) {
    return (unsigned)f2bf(a) | ((unsigned)f2bf(b) << 16);
}

// ---------------- 1. prep: GN partials + weight bf16 conversion ----------------
__global__ __launch_bounds__(256) void prep_kernel(const float* __restrict__ x,
                                                   const float* __restrict__ qw,
                                                   const float* __restrict__ pw,
                                                   float* __restrict__ stats2,
                                                   u16* __restrict__ qwbf,
                                                   u16* __restrict__ pwbf) {
    int blk = blockIdx.x;
    if (blk < 256) {
        __shared__ float rs[4], rss[4];
        int bg = blk >> 3, chunk = blk & 7;
        const float4* xp = (const float4*)(x + (size_t)bg * (CperG * N_)) + chunk * 2048;
        float s = 0.f, ss = 0.f;
        for (int i = threadIdx.x; i < 2048; i += 256) {
            float4 v = xp[i];
            s  += v.x + v.y + v.z + v.w;
            ss += v.x*v.x + v.y*v.y + v.z*v.z + v.w*v.w;
        }
        #pragma unroll
        for (int off = 32; off > 0; off >>= 1) {
            s  += __shfl_down(s, off);
            ss += __shfl_down(ss, off);
        }
        int wv = threadIdx.x >> 6, ln = threadIdx.x & 63;
        if (ln == 0) { rs[wv] = s; rss[wv] = ss; }
        __syncthreads();
        if (threadIdx.x == 0) {
            stats2[blk*2]     = rs[0] + rs[1] + rs[2] + rs[3];
            stats2[blk*2 + 1] = rss[0] + rss[1] + rss[2] + rss[3];
        }
    } else {
        int fidx = ((blk - 256) * 256 + threadIdx.x) * 4;
        float4 v;
        u16* dst;
        if (fidx < 3*C_*C_) { v = *(const float4*)(qw + fidx); dst = qwbf + fidx; }
        else { int j = fidx - 3*C_*C_; v = *(const float4*)(pw + j); dst = pwbf + j; }
        ushort4 o;
        o.x = f2bf(v.x); o.y = f2bf(v.y); o.z = f2bf(v.z); o.w = f2bf(v.w);
        *(ushort4*)dst = o;
    }
}

// ---------------- 2. QKV via MFMA -> Q row-major; K,V in MFMA-FRAGMENT order -------
// Ksw frag(b, T, cc) [T=key/32, cc=chan/16]: 512 u16; lane l holds K[32T+(l&31)]
//   [16cc + 8*(l>>5) + 0..8)  -> 1 coalesced b128 per frag in attn.
// Vsw frag(b, ct, T, kk) [ct=chan/32, kk=(key&31)/16]: lane l holds
//   V[32ct+(l&31)][32T+16kk + {4*(l>>5)+0..3, 8+4*(l>>5)+0..3}] — exactly the
//   element order of r9's silicon-verified LDS reads (q[0]/q[1] halves).
constexpr int HS = 136;   // padded row stride (u16)

__global__ __launch_bounds__(256, 2) void qkv_kernel(const float* __restrict__ x,
                                                     const float* __restrict__ stats2,
                                                     const float* __restrict__ nw,
                                                     const float* __restrict__ nb,
                                                     const u16* __restrict__ qwbf,
                                                     const float* __restrict__ qb,
                                                     u16* __restrict__ Qt,
                                                     u16* __restrict__ Ksw,
                                                     u16* __restrict__ Vsw,
                                                     float* __restrict__ qn2,
                                                     int* __restrict__ kmaxI) {
    int n0 = (blockIdx.x & 63) * 64;
    int b  = blockIdx.x >> 6;
    __shared__ u16 hs[64 * HS];
    __shared__ u16 Wl[64 * HS];
    __shared__ float gmean[8], grstd[8];
    int t = threadIdx.x;
    const float invM = 1.f / (float)(CperG * N_);
    if (t < 8) {
        const float* sp = stats2 + (size_t)(b*G_ + t)*16;
        float S = 0.f, SS = 0.f;
        #pragma unroll
        for (int k2 = 0; k2 < 8; ++k2) { S += sp[k2*2]; SS += sp[k2*2 + 1]; }
        float mean = S * invM;
        gmean[t] = mean;
        grstd[t] = rsqrtf(SS * invM - mean*mean + EPS_);
    }
    __syncthreads();
    #pragma unroll
    for (int r = 0; r < 8; ++r) {
        int idx = t + (r << 8);
        int c = idx >> 4, n4 = idx & 15;
        int g = c >> 4;
        float wgt = nw[c] * grstd[g];
        float bia = nb[c] - gmean[g] * wgt;
        float4 xv = *(const float4*)(x + ((size_t)(b*C_ + c))*N_ + n0 + n4*4);
        int base = (n4*4) * HS + c;
        hs[base         ] = f2bf(xv.x*wgt + bia);
        hs[base +     HS] = f2bf(xv.y*wgt + bia);
        hs[base + 2 * HS] = f2bf(xv.z*wgt + bia);
        hs[base + 3 * HS] = f2bf(xv.w*wgt + bia);
    }
    __syncthreads();
    int w = t >> 6, lane = t & 63, lo = lane & 15, hi = lane >> 4;
    bf16x8 hf[4];
    #pragma unroll
    for (int ch = 0; ch < 4; ++ch)
        hf[ch] = *(const bf16x8*)(hs + (16*w + lo)*HS + 32*ch + 8*hi);

    int Tb = (n0 >> 5) + (w >> 1);       // key tile this wave contributes to
    float nq = 0.f, nk = 0.f;
    for (int ck = 0; ck < 6; ++ck) {
        {
            int r = t >> 2, p = t & 3;
            const u16* src = qwbf + (size_t)(ck*64 + r)*C_ + p*32;
            u16* dst = Wl + r*HS + p*32;
            #pragma unroll
            for (int k2 = 0; k2 < 4; ++k2)
                *(uint4*)(dst + 8*k2) = *(const uint4*)(src + 8*k2);
        }
        __syncthreads();
        #pragma unroll
        for (int ot = 0; ot < 4; ++ot) {
            int o16 = ck*64 + ot*16;
            bf16x8 wf[4];
            #pragma unroll
            for (int ch = 0; ch < 4; ++ch)
                wf[ch] = *(const bf16x8*)(Wl + (ot*16 + lo)*HS + 32*ch + 8*hi);
            if (o16 < 2*C_) {
                // Q/K: A=W (m=o), B=h (n=px) -> lane holds D[o=o16+4hi+r][px=n0+16w+lo]
                f32x4 acc = (f32x4){0.f, 0.f, 0.f, 0.f};
                #pragma unroll
                for (int ch = 0; ch < 4; ++ch)
                    acc = __builtin_amdgcn_mfma_f32_16x16x32_bf16(wf[ch], hf[ch], acc, 0, 0, 0);
                float4 bv = *(const float4*)(qb + o16 + 4*hi);
                int n = n0 + 16*w + lo;
                ushort4 o4;
                if (o16 < C_) {
                    float q0 = (acc[0] + bv.x) * SCALE_;
                    float q1 = (acc[1] + bv.y) * SCALE_;
                    float q2 = (acc[2] + bv.z) * SCALE_;
                    float q3 = (acc[3] + bv.w) * SCALE_;
                    nq += (q0*q0 + q1*q1) + (q2*q2 + q3*q3);
                    o4.x = f2bf(q0); o4.y = f2bf(q1); o4.z = f2bf(q2); o4.w = f2bf(q3);
                    *(ushort4*)(Qt + ((size_t)b*N_ + n)*C_ + o16 + 4*hi) = o4;
                } else {
                    float k0 = acc[0] + bv.x, k1 = acc[1] + bv.y;
                    float k2 = acc[2] + bv.z, k3 = acc[3] + bv.w;
                    nk += (k0*k0 + k1*k1) + (k2*k2 + k3*k3);
                    o4.x = f2bf(k0); o4.y = f2bf(k1); o4.z = f2bf(k2); o4.w = f2bf(k3);
                    // K frag scatter: c = o16-128+4hi+r; cc = (o16-128)>>4;
                    // lane' = (n&31) + 32*(hi>>1); elem off = 4*(hi&1)+r
                    int cc = (o16 - C_) >> 4;
                    int lp = (16*(w & 1) + lo) + 32*(hi >> 1);
                    size_t fb = ((size_t)(b*128 + Tb)*8 + cc)*512;
                    *(ushort4*)(Ksw + fb + lp*8 + 4*(hi & 1)) = o4;
                }
            } else {
                // V: A=h (m=px), B=W (n=o) -> lane holds D[px=n0+16w+4hi+r][o=o16-256+lo]
                f32x4 acc = (f32x4){0.f, 0.f, 0.f, 0.f};
                #pragma unroll
                for (int ch = 0; ch < 4; ++ch)
                    acc = __builtin_amdgcn_mfma_f32_16x16x32_bf16(hf[ch], wf[ch], acc, 0, 0, 0);
                float bia = qb[o16 + lo];
                ushort4 o4;
                o4.x = f2bf(acc[0] + bia);
                o4.y = f2bf(acc[1] + bia);
                o4.z = f2bf(acc[2] + bia);
                o4.w = f2bf(acc[3] + bia);
                // V frag scatter: keys n0+16w+4hi+r, chan c = o16-256+lo;
                // ct = m>>1 (m=(o16-256)>>4); kk = w&1;
                // lane' = (c&31) + 32*(hi&1); elem off = 4*(hi>>1)+r
                int m  = (o16 - 2*C_) >> 4;
                int ct = m >> 1;
                int lp = (16*(m & 1) + lo) + 32*(hi & 1);
                size_t fb = (((size_t)(b*4 + ct)*128 + Tb)*2 + (w & 1))*512;
                *(ushort4*)(Vsw + fb + lp*8 + 4*(hi >> 1)) = o4;
            }
        }
        __syncthreads();
    }
    nq += __shfl_xor(nq, 16); nq += __shfl_xor(nq, 32);
    nk += __shfl_xor(nk, 16); nk += __shfl_xor(nk, 32);
    if (lane < 16) qn2[(size_t)b*N_ + n0 + 16*w + lo] = nq;
    #pragma unroll
    for (int off = 1; off < 16; off <<= 1)
        nk = fmaxf(nk, __shfl_xor(nk, off));
    if (lane == 0) atomicMax(&kmaxI[b], __float_as_int(nk));  // poison negative: safe
}

// ------------- 3. Streaming MFMA attention: no LDS, no barriers in the loop -------------
// 256 blocks (1/CU), 512 thr, 8 waves = (qt: 2 x 32-q) x (ks: 4 key stripes of
// 1024 keys = 32 tiles). Every K/V fragment is one coalesced b128 from the
// pre-swizzled buffers (L2-resident). Bound softmax (shared m_q) keeps the loop
// reduction-free; waves drift freely, vmcnt paces the stream (AITER pattern).
__global__ __launch_bounds__(512, 2) void attn_kernel(const u16* __restrict__ Qt,
                                                      const u16* __restrict__ Ksw,
                                                      const u16* __restrict__ Vsw,
                                                      const float* __restrict__ qn2,
                                                      const int* __restrict__ kmaxI,
                                                      const u16* __restrict__ pwbf,
                                                      const float* __restrict__ pb,
                                                      const float* __restrict__ x,
                                                      float* __restrict__ out) {
    int lb = blockIdx.x;
    int b  = lb & 3;                       // XCD-swizzle: batch locality in L2
    int i0 = 64 * (lb >> 2);
    int t = threadIdx.x;
    int w = t >> 6, lane = t & 63;
    int l31 = lane & 31, h = lane >> 5;
    int qt = w >> 2, ks = w & 3;

    __shared__ float Ob[64 * 132];         // combined O (33.8 KB)
    __shared__ float lW[8][32];

    float kmax = sqrtf(__int_as_float(kmaxI[b]));
    float mq = sqrtf(qn2[(size_t)b*N_ + i0 + 32*qt + l31]) * kmax * 1.02f + 1e-6f;

    // persistent Q B-frags (query = i0 + 32qt + l31, chans 16cc + 8h)
    const u16* Qb = Qt + (size_t)b*N_*C_;
    bf16x8 qf[8];
    #pragma unroll
    for (int cc = 0; cc < 8; ++cc)
        qf[cc] = *(const bf16x8*)(Qb + (size_t)(i0 + 32*qt + l31)*C_ + 16*cc + 8*h);

    f32x16 acc[4];
    #pragma unroll
    for (int ct = 0; ct < 4; ++ct)
        #pragma unroll
        for (int r = 0; r < 16; ++r) acc[ct][r] = 0.f;
    float psum = 0.f;

    const u16* Kbase = Ksw + ((size_t)(b*128 + ks*32)*8)*512;   // stripe tile 0
    bf16x8 kf[8], kn[8];
    #pragma unroll
    for (int cc = 0; cc < 8; ++cc)
        kf[cc] = *(const bf16x8*)(Kbase + cc*512 + lane*8);

    for (int it = 0; it < 32; ++it) {
        // ---- QK: one 32x32 S^T tile (keys of tile T, queries 32qt..+32) ----
        f32x16 s;
        #pragma unroll
        for (int r = 0; r < 16; ++r) s[r] = 0.f;
        #pragma unroll
        for (int cc = 0; cc < 8; ++cc)
            s = __builtin_amdgcn_mfma_f32_32x32x16_bf16(kf[cc], qf[cc], s, 0, 0, 0);
        // ---- prefetch K for tile it+1 (wrap on last: redundant, in-bounds) ----
        {
            const u16* Kn = Kbase + ((size_t)(((it + 1) & 31))*8)*512;
            #pragma unroll
            for (int cc = 0; cc < 8; ++cc)
                kn[cc] = *(const bf16x8*)(Kn + cc*512 + lane*8);
        }
        // ---- V fragments for current tile (coalesced b128 each) ----
        int T = ks*32 + it;
        bf16x8 v1[4], v2[4];
        #pragma unroll
        for (int ct = 0; ct < 4; ++ct) {
            const u16* vb = Vsw + (((size_t)(b*4 + ct)*128 + T)*2)*512;
            v1[ct] = *(const bf16x8*)(vb + lane*8);
            v2[ct] = *(const bf16x8*)(vb + 512 + lane*8);
        }
        // ---- bound softmax: p = exp(S - m_q), no reductions, no LDS ----
        float p[16];
        #pragma unroll
        for (int r = 0; r < 16; ++r) {
            p[r] = __expf(s[r] - mq);
            psum += p[r];
        }
        union { bf16x8 v; unsigned u[4]; } pf1, pf2;
        pf1.u[0] = pk2(p[0],  p[1]);  pf1.u[1] = pk2(p[2],  p[3]);
        pf1.u[2] = pk2(p[4],  p[5]);  pf1.u[3] = pk2(p[6],  p[7]);
        pf2.u[0] = pk2(p[8],  p[9]);  pf2.u[1] = pk2(p[10], p[11]);
        pf2.u[2] = pk2(p[12], p[13]); pf2.u[3] = pk2(p[14], p[15]);
        // ---- PV: A = V frags (regs), B = P (regs) — no LDS round-trip ----
        #pragma unroll
        for (int ct = 0; ct < 4; ++ct) {
            acc[ct] = __builtin_amdgcn_mfma_f32_32x32x16_bf16(v1[ct], pf1.v, acc[ct], 0, 0, 0);
            acc[ct] = __builtin_amdgcn_mfma_f32_32x32x16_bf16(v2[ct], pf2.v, acc[ct], 0, 0, 0);
        }
        // rotate K prefetch
        #pragma unroll
        for (int cc = 0; cc < 8; ++cc) kf[cc] = kn[cc];
    }

    // ---------------- combine ks stripes (plain adds: shared m_q) ----------------
    psum += __shfl_xor(psum, 32);
    if (lane < 32) lW[w][l31] = psum;
    for (int i = 0; i < 4; ++i) {
        if (ks == i) {
            int q = 32*qt + l31;
            #pragma unroll
            for (int ct = 0; ct < 4; ++ct)
                #pragma unroll
                for (int qd = 0; qd < 4; ++qd) {
                    int c = 32*ct + 8*qd + 4*h;
                    float4 vv;
                    vv.x = acc[ct][4*qd + 0];
                    vv.y = acc[ct][4*qd + 1];
                    vv.z = acc[ct][4*qd + 2];
                    vv.w = acc[ct][4*qd + 3];
                    if (i == 0) {
                        *(float4*)(Ob + q*132 + c) = vv;
                    } else {
                        float4 o = *(const float4*)(Ob + q*132 + c);
                        o.x += vv.x; o.y += vv.y; o.z += vv.z; o.w += vv.w;
                        *(float4*)(Ob + q*132 + c) = o;
                    }
                }
        }
        __syncthreads();
    }
    // ---------------- proj + bias + residual (verified r9 epilogue) ----------------
    int lo = lane & 15, hi = lane >> 4;
    int qtile = w >> 1, os = w & 1;
    int q = 16*qtile + lo;
    int qg = 4*(q >> 5), qc = q & 31;
    float linv = 1.f / (lW[qg][qc] + lW[qg+1][qc] + lW[qg+2][qc] + lW[qg+3][qc]);
    bf16x8 aa[4];
    #pragma unroll
    for (int ch = 0; ch < 4; ++ch) {
        float4 ua = *(const float4*)(Ob + q*132 + 32*ch + 8*hi);
        float4 ub = *(const float4*)(Ob + q*132 + 32*ch + 8*hi + 4);
        union { bf16x8 hh; unsigned u[4]; } pkd;
        pkd.u[0] = pk2(ua.x*linv, ua.y*linv);
        pkd.u[1] = pk2(ua.z*linv, ua.w*linv);
        pkd.u[2] = pk2(ub.x*linv, ub.y*linv);
        pkd.u[3] = pk2(ub.z*linv, ub.w*linv);
        aa[ch] = pkd.hh;
    }
    #pragma unroll
    for (int ot = 0; ot < 4; ++ot) {
        int ob = 64*os + 16*ot;
        f32x4 pr = (f32x4){0.f, 0.f, 0.f, 0.f};
        #pragma unroll
        for (int ch = 0; ch < 4; ++ch) {
            bf16x8 bw = *(const bf16x8*)(pwbf + (size_t)(ob + lo)*C_ + 32*ch + 8*hi);
            pr = __builtin_amdgcn_mfma_f32_16x16x32_bf16(aa[ch], bw, pr, 0, 0, 0);
        }
        int o = ob + lo;
        float pbv = pb[o];
        size_t base = ((size_t)(b*C_ + o))*N_ + i0 + 16*qtile + 4*hi;
        float4 xr = *(const float4*)(x + base);
        float4 res;
        res.x = xr.x + pr[0] + pbv;
        res.y = xr.y + pr[1] + pbv;
        res.z = xr.z + pr[2] + pbv;
        res.w = xr.w + pr[3] + pbv;
        *(float4*)(out + base) = res;
    }
}

extern "C" void kernel_launch(void* const* d_in, const int* in_sizes, int n_in,
                              void* d_out, int out_size, void* d_ws, size_t ws_size,
                              hipStream_t stream) {
    const float* x  = (const float*)d_in[0];
    const float* nw = (const float*)d_in[1];
    const float* nb = (const float*)d_in[2];
    const float* qw = (const float*)d_in[3];
    const float* qb = (const float*)d_in[4];
    const float* pw = (const float*)d_in[5];
    const float* pb = (const float*)d_in[6];
    float* out = (float*)d_out;

    // ws: [stats2 2KB][qn2 64KB][kmaxI 256B][qwbf 96KB][pwbf 32KB][Qt 4MB][Ksw 4MB][Vsw 4MB]
    char* p = (char*)d_ws;
    float* stats2 = (float*)p;                 p += 2048;
    float* qn2    = (float*)p;                 p += (size_t)B_*N_*4;
    int*   kmaxI  = (int*)p;                   p += 256;
    u16*   qwbf   = (u16*)p;                   p += (size_t)3*C_*C_*2;
    u16*   pwbf   = (u16*)p;                   p += (size_t)C_*C_*2;
    u16*   Qt     = (u16*)p;                   p += (size_t)B_*N_*C_*2;
    u16*   Ksw    = (u16*)p;                   p += (size_t)B_*N_*C_*2;
    u16*   Vsw    = (u16*)p;

    prep_kernel<<<dim3(320), 256, 0, stream>>>(x, qw, pw, stats2, qwbf, pwbf);
    qkv_kernel<<<dim3(256), 256, 0, stream>>>(x, stats2, nw, nb, qwbf, qb,
                                              Qt, Ksw, Vsw, qn2, kmaxI);
    attn_kernel<<<dim3(256), 512, 0, stream>>>(Qt, Ksw, Vsw, qn2, kmaxI,
                                               pwbf, pb, x, out);
}